// Round 3
// baseline (549.749 us; speedup 1.0000x reference)
//
#include <hip/hip_runtime.h>

// Problem constants: B=256 batch, N=256 generators, D=512 dims.
#define BB 256
#define NN 256
#define DD 512
#define RT (NN + DD)            // 768 rows per batch in new_pd
#define D4 (DD / 4)             // 128 float4 per row

constexpr float EPSF = 1e-8f;
constexpr size_t PD_OFF = (size_t)BB * DD;                  // new_central elems
constexpr size_t NE_OFF = PD_OFF + (size_t)BB * RT * DD;    // + new_pd elems

typedef float vfloat4 __attribute__((ext_vector_type(4)));

// NOTE: never use (vfloat4)(a,b,c,d) — in C++ that is a cast of a COMMA
// EXPRESSION (splat of the last value), not an OpenCL vector literal. That
// single line corrupted the radius in rounds 1-2. Components are always
// written explicitly below.

__device__ __forceinline__ vfloat4 nt_load4(const vfloat4* p) {
    return __builtin_nontemporal_load(p);
}
__device__ __forceinline__ void nt_store4(vfloat4* p, vfloat4 v) {
    __builtin_nontemporal_store(v, p);
}

// Per-dim relaxation, matching the reference exactly (identical to the
// round-0 kernel that passed).
__device__ __forceinline__ void relax1(float rad, float c,
                                       float& l, float& beta) {
    const float lo = c - rad, up = c + rad;
    const float rl = fmaxf(lo, 0.f), ru = fmaxf(up, 0.f);
    l = (ru - rl) / (up - lo + EPSF);
    if (lo >= 0.f) l = 1.f;
    if (up <  0.f) l = 0.f;
    if (l != l)    l = 0.f;                    // nan_to_num
    l = fminf(fmaxf(l, 0.f), 1.f);             // clip
    beta = (rl - l * lo) * 0.5f;               // note: beta >= 0 in all cases
}

// ---------------- K1: radius reduction + relaxation ------------------------
// One block per batch. 1024 threads: d4 = tid&127 (float4 column), rg =
// tid>>7 (row group). Each iteration reads 8 complete rows = 16 KB fully
// contiguous. No workspace: lam is parked in the new_err slot of out, beta
// in the new_central slot; K3 finalizes both after K2 has consumed them.
__global__ __launch_bounds__(1024) void reduce_kernel(
    const float* __restrict__ cv, const float* __restrict__ pd,
    const float* __restrict__ err, float* __restrict__ out)
{
    const int b   = blockIdx.x;
    const int tid = threadIdx.x;
    const int d4  = tid & (D4 - 1);
    const int rg  = tid >> 7;

    const vfloat4* pdb = (const vfloat4*)pd + (size_t)b * NN * D4;
    float ax = 0.f, ay = 0.f, az = 0.f, aw = 0.f;
#pragma unroll 8
    for (int it = 0; it < NN / 8; ++it) {
        vfloat4 v = nt_load4(pdb + (size_t)((it << 3) + rg) * D4 + d4);
        ax += fabsf(v.x); ay += fabsf(v.y); az += fabsf(v.z); aw += fabsf(v.w);
    }

    __shared__ vfloat4 part[8][D4];            // 16 KB
    {
        vfloat4 s;                             // explicit components (see NOTE)
        s.x = ax; s.y = ay; s.z = az; s.w = aw;
        part[rg][d4] = s;
    }
    __syncthreads();

    if (tid < D4) {                            // 128 threads finish 512 dims
        vfloat4 rad = part[0][tid];
#pragma unroll
        for (int g = 1; g < 8; ++g) {
            vfloat4 p = part[g][tid];
            rad.x += p.x; rad.y += p.y; rad.z += p.z; rad.w += p.w;
        }
        const size_t gi4 = (size_t)b * D4 + tid;
        const vfloat4 c = ((const vfloat4*)cv)[gi4];
        const vfloat4 e = ((const vfloat4*)err)[gi4];
        vfloat4 l4, b4;
        float l, beta;
        relax1(rad.x + fabsf(e.x), c.x, l, beta);  l4.x = l; b4.x = beta;
        relax1(rad.y + fabsf(e.y), c.y, l, beta);  l4.y = l; b4.y = beta;
        relax1(rad.z + fabsf(e.z), c.z, l, beta);  l4.z = l; b4.z = beta;
        relax1(rad.w + fabsf(e.w), c.w, l, beta);  l4.w = l; b4.w = beta;
        // Park intermediates in out (plain cached stores; re-read by K2/K3):
        ((vfloat4*)(out + NE_OFF))[gi4] = l4;      // lam -> new_err slot
        ((vfloat4*)out)[gi4]            = b4;      // beta -> new_central slot
    }
}

// ---------------- K2: pure linear stream of new_pd -------------------------
// 2048 blocks x 256 threads. Each block owns 96 CONTIGUOUS rows (192 KB) of
// new_pd; 96 | 768 so each block stays inside one batch and the scale/diag
// branch is wave-uniform (each wave covers half of one row). Every big load
// and store is fully coalesced and monotonically increasing — the pattern
// the 6.35 TB/s fill kernel proves works. lam/beta reads are 1 MB total,
// L3-resident.
#define WBLOCKS 2048
#define RPB (BB * RT / WBLOCKS)   // 96 rows per block

__global__ __launch_bounds__(256) void pd_kernel(
    const float* __restrict__ pd, float* out /* aliased read+write: no restrict */)
{
    const int bx  = blockIdx.x;
    const int b   = bx >> 3;                  // 8 blocks per batch
    const int tid = threadIdx.x;
    const int d4  = tid & (D4 - 1);
    const int ro  = tid >> 7;                 // which of 2 rows per iter

    const vfloat4 lm  = ((const vfloat4*)(out + NE_OFF))[(size_t)b * D4 + d4];
    const float*  bet = out + (size_t)b * DD;            // beta row (diag vals)
    const vfloat4* pdb  = (const vfloat4*)pd + (size_t)b * NN * D4;
    vfloat4*       outb = (vfloat4*)(out + PD_OFF) + (size_t)b * RT * D4;

    int r = (bx & 7) * RPB + ro;
#pragma unroll 4
    for (int i = 0; i < RPB / 2; ++i, r += 2) {
        vfloat4 v;
        if (r < NN) {
            vfloat4 pv = nt_load4(pdb + (size_t)r * D4 + d4);
            v.x = pv.x * lm.x; v.y = pv.y * lm.y;
            v.z = pv.z * lm.z; v.w = pv.w * lm.w;
        } else {
            const int dg = r - NN;            // diag row 0..511
            v.x = 0.f; v.y = 0.f; v.z = 0.f; v.w = 0.f;
            if (d4 == (dg >> 2))
                v[dg & 3] = fabsf(bet[dg]);   // delta = |beta|
        }
        nt_store4(outb + (size_t)r * D4 + d4, v);
    }
}

// ---------------- K3: finalize new_central / new_err in place --------------
// Runs after K2 has consumed the parked lam/beta. 32768 float4 of work.
__global__ __launch_bounds__(256) void finalize_kernel(
    const float* __restrict__ cv, const float* __restrict__ err,
    float* out /* read+write same slots: no restrict */)
{
    const size_t i = (size_t)blockIdx.x * 256 + threadIdx.x;  // 0..32767
    const vfloat4 l  = ((const vfloat4*)(out + NE_OFF))[i];   // lam
    const vfloat4 bt = ((const vfloat4*)out)[i];              // beta
    const vfloat4 c  = ((const vfloat4*)cv)[i];
    const vfloat4 e  = ((const vfloat4*)err)[i];
    vfloat4 nc, ne;
    nc.x = l.x * c.x + bt.x;  ne.x = l.x * e.x;
    nc.y = l.y * c.y + bt.y;  ne.y = l.y * e.y;
    nc.z = l.z * c.z + bt.z;  ne.z = l.z * e.z;
    nc.w = l.w * c.w + bt.w;  ne.w = l.w * e.w;
    ((vfloat4*)out)[i]            = nc;       // new_central
    ((vfloat4*)(out + NE_OFF))[i] = ne;       // new_err
}

extern "C" void kernel_launch(void* const* d_in, const int* in_sizes, int n_in,
                              void* d_out, int out_size, void* d_ws, size_t ws_size,
                              hipStream_t stream) {
    const float* cv  = (const float*)d_in[0];
    const float* pd  = (const float*)d_in[1];
    const float* err = (const float*)d_in[2];
    float* out = (float*)d_out;

    reduce_kernel<<<dim3(BB), dim3(1024), 0, stream>>>(cv, pd, err, out);
    pd_kernel<<<dim3(WBLOCKS), dim3(256), 0, stream>>>(pd, out);
    finalize_kernel<<<dim3(BB * DD / 4 / 256), dim3(256), 0, stream>>>(cv, err, out);
}

// Round 6
// 514.402 us; speedup vs baseline: 1.0687x; 1.0687x over previous
//
#include <hip/hip_runtime.h>

// Problem constants: B=256 batch, N=256 generators, D=512 dims.
#define BB 256
#define NN 256
#define DD 512
#define RT (NN + DD)            // 768 rows per batch in new_pd
#define D4 (DD / 4)             // 128 float4 per row

constexpr float EPSF = 1e-8f;
constexpr size_t PD_OFF = (size_t)BB * DD;                  // new_central elems
constexpr size_t NE_OFF = PD_OFF + (size_t)BB * RT * DD;    // + new_pd elems

typedef float vfloat4 __attribute__((ext_vector_type(4)));

// RULES (learned rounds 1-3):
//  * never (vfloat4)(a,b,c,d)  -- C++ parses it as a comma-expression cast
//    (splat of the last element). Write components explicitly.
//  * never v[runtime_idx] on a vector in a hot loop -- risks scratch demotion
//    (rule #20). The diag path below has NO per-element logic at all.

__device__ __forceinline__ void nt_store4(vfloat4* p, vfloat4 v) {
    __builtin_nontemporal_store(v, p);
}

// Per-dim relaxation, matching the reference exactly.
__device__ __forceinline__ void relax1(float rad, float c,
                                       float& l, float& beta) {
    const float lo = c - rad, up = c + rad;
    const float rl = fmaxf(lo, 0.f), ru = fmaxf(up, 0.f);
    l = (ru - rl) / (up - lo + EPSF);
    if (lo >= 0.f) l = 1.f;
    if (up <  0.f) l = 0.f;
    if (l != l)    l = 0.f;                    // nan_to_num
    l = fminf(fmaxf(l, 0.f), 1.f);             // clip
    beta = (rl - l * lo) * 0.5f;               // beta >= 0 in all cases
}

// ---------------- K1: radius reduction + relaxation ------------------------
// One block per batch, 1024 threads. Row-linear 16 KB-contiguous reads.
// REGULAR cached loads on purpose: pd is 128 MiB and fits the 256 MiB L3,
// so K2's re-read of pd becomes an L3 hit. lam parks in the new_err slot,
// beta in the new_central slot; K3 finalizes both after K2 consumed them.
__global__ __launch_bounds__(1024) void reduce_kernel(
    const float* __restrict__ cv, const float* __restrict__ pd,
    const float* __restrict__ err, float* __restrict__ out)
{
    const int b   = blockIdx.x;
    const int tid = threadIdx.x;
    const int d4  = tid & (D4 - 1);
    const int rg  = tid >> 7;

    const vfloat4* pdb = (const vfloat4*)pd + (size_t)b * NN * D4;
    float ax = 0.f, ay = 0.f, az = 0.f, aw = 0.f;
#pragma unroll 8
    for (int it = 0; it < NN / 8; ++it) {
        vfloat4 v = pdb[(size_t)((it << 3) + rg) * D4 + d4];   // cached load
        ax += fabsf(v.x); ay += fabsf(v.y); az += fabsf(v.z); aw += fabsf(v.w);
    }

    __shared__ vfloat4 part[8][D4];            // 16 KB
    {
        vfloat4 s;
        s.x = ax; s.y = ay; s.z = az; s.w = aw;
        part[rg][d4] = s;
    }
    __syncthreads();

    if (tid < D4) {                            // 128 threads finish 512 dims
        vfloat4 rad = part[0][tid];
#pragma unroll
        for (int g = 1; g < 8; ++g) {
            vfloat4 p = part[g][tid];
            rad.x += p.x; rad.y += p.y; rad.z += p.z; rad.w += p.w;
        }
        const size_t gi4 = (size_t)b * D4 + tid;
        const vfloat4 c = ((const vfloat4*)cv)[gi4];
        const vfloat4 e = ((const vfloat4*)err)[gi4];
        vfloat4 l4, b4;
        float l, beta;
        relax1(rad.x + fabsf(e.x), c.x, l, beta);  l4.x = l; b4.x = beta;
        relax1(rad.y + fabsf(e.y), c.y, l, beta);  l4.y = l; b4.y = beta;
        relax1(rad.z + fabsf(e.z), c.z, l, beta);  l4.z = l; b4.z = beta;
        relax1(rad.w + fabsf(e.w), c.w, l, beta);  l4.w = l; b4.w = beta;
        ((vfloat4*)(out + NE_OFF))[gi4] = l4;      // lam  -> new_err slot
        ((vfloat4*)out)[gi4]            = b4;      // beta -> new_central slot
    }
}

// ---------------- K2: scale-stream + zero-blast ----------------------------
// 4096 blocks x 256 threads, split by block range (grid-uniform branch):
//   blocks 0..2047   : scale rows. 32 contiguous rows (64 KB) per block.
//                      pd read is an L3 hit (primed by K1); linear NT store.
//                      No branches, no dynamic indexing in the loop.
//   blocks 2048..4095: zero-blast of the 268 MB diag region -- EXACTLY the
//                      fill kernel's pattern (contiguous 4 KB per block-iter,
//                      pure NT stores), which measures 6.35 TB/s.
__global__ __launch_bounds__(256) void pd_kernel(
    const float* __restrict__ pd, float* out /* aliased: no restrict */)
{
    const int bx  = blockIdx.x;
    const int tid = threadIdx.x;

    if (bx < 2048) {
        const int b  = bx >> 3;               // 8 blocks per batch
        const int d4 = tid & (D4 - 1);
        const int ro = tid >> 7;              // which of 2 rows per iter
        const vfloat4 lm = ((const vfloat4*)(out + NE_OFF))[(size_t)b * D4 + d4];
        const vfloat4* pdb  = (const vfloat4*)pd + (size_t)b * NN * D4;
        vfloat4*       outb = (vfloat4*)(out + PD_OFF) + (size_t)b * RT * D4;

        int r = (bx & 7) * 32 + ro;           // rows r0..r0+31
#pragma unroll 4
        for (int i = 0; i < 16; ++i, r += 2) {
            vfloat4 pv = pdb[(size_t)r * D4 + d4];         // L3-hit load
            vfloat4 v;
            v.x = pv.x * lm.x; v.y = pv.y * lm.y;
            v.z = pv.z * lm.z; v.w = pv.w * lm.w;
            nt_store4(outb + (size_t)r * D4 + d4, v);
        }
    } else {
        const int zb = bx - 2048;
        const int b  = zb >> 3;               // 8 blocks per batch
        // diag region of batch b: 512 rows * 128 float4 = 65536 float4
        vfloat4* base = (vfloat4*)(out + PD_OFF) + (size_t)b * RT * D4
                      + (size_t)NN * D4 + (size_t)(zb & 7) * 8192;
        vfloat4 z;
        z.x = 0.f; z.y = 0.f; z.z = 0.f; z.w = 0.f;
#pragma unroll 8
        for (int it = 0; it < 32; ++it)
            nt_store4(base + it * 256 + tid, z);
    }
}

// ---------------- K3: diag scatter + finalize ------------------------------
// One block per batch, 256 threads.
// Phase 1: scatter the 512 |beta| values onto the (already zeroed) diagonal.
// Phase 2 (after barrier): overwrite the parked slots with new_central /
// new_err.
__global__ __launch_bounds__(256) void finalize_kernel(
    const float* __restrict__ cv, const float* __restrict__ err,
    float* out /* read+write same slots: no restrict */)
{
    const int b   = blockIdx.x;
    const int tid = threadIdx.x;
    const float* bet = out + (size_t)b * DD;              // parked beta row

    const float b0 = bet[tid];
    const float b1 = bet[tid + 256];
    float* diag = out + PD_OFF + (size_t)b * RT * DD + (size_t)NN * DD;
    diag[(size_t)tid * DD + tid]                 = fabsf(b0);   // row tid, col tid
    diag[(size_t)(tid + 256) * DD + (tid + 256)] = fabsf(b1);

    __syncthreads();

    if (tid < D4) {
        const size_t gi4 = (size_t)b * D4 + tid;
        const vfloat4 l  = ((const vfloat4*)(out + NE_OFF))[gi4];  // lam
        const vfloat4 bt = ((const vfloat4*)out)[gi4];             // beta
        const vfloat4 c  = ((const vfloat4*)cv)[gi4];
        const vfloat4 e  = ((const vfloat4*)err)[gi4];
        vfloat4 nc, ne;
        nc.x = l.x * c.x + bt.x;  ne.x = l.x * e.x;
        nc.y = l.y * c.y + bt.y;  ne.y = l.y * e.y;
        nc.z = l.z * c.z + bt.z;  ne.z = l.z * e.z;
        nc.w = l.w * c.w + bt.w;  ne.w = l.w * e.w;
        ((vfloat4*)out)[gi4]            = nc;     // new_central
        ((vfloat4*)(out + NE_OFF))[gi4] = ne;     // new_err
    }
}

extern "C" void kernel_launch(void* const* d_in, const int* in_sizes, int n_in,
                              void* d_out, int out_size, void* d_ws, size_t ws_size,
                              hipStream_t stream) {
    const float* cv  = (const float*)d_in[0];
    const float* pd  = (const float*)d_in[1];
    const float* err = (const float*)d_in[2];
    float* out = (float*)d_out;

    reduce_kernel<<<dim3(BB), dim3(1024), 0, stream>>>(cv, pd, err, out);
    pd_kernel<<<dim3(4096), dim3(256), 0, stream>>>(pd, out);
    finalize_kernel<<<dim3(BB), dim3(256), 0, stream>>>(cv, err, out);
}